// Round 10
// baseline (2393.598 us; speedup 1.0000x reference)
//
#include <hip/hip_runtime.h>

typedef unsigned int u32;
typedef unsigned short u16;
typedef unsigned long long u64;

typedef __attribute__((ext_vector_type(8))) short bf16x8;
typedef __attribute__((ext_vector_type(4))) float f32x4;

__device__ __forceinline__ u16 f2bf(float f) {
    u32 u = __float_as_uint(f);
    u += 0x7fffu + ((u >> 16) & 1u);
    return (u16)(u >> 16);
}
__device__ __forceinline__ float bf2f(u16 h) {
    return __uint_as_float(((u32)h) << 16);
}

// ---------------------------------------------------------------------------
// prep: convert/transpose weights to bf16; zero ring slot 0 of hbuf1 (full
// 256-deep ring) and hbuf2 (8-deep ring) + the 32-u32 control block.
// Stale slots >0 from a previous launch are harmless: consumers are gated by
// the freshly-zeroed sentinels and only read a slot after this launch's
// producers wrote it.
// Items: 240000+240000+480000+120000 + 51200 + 25600 + 32 = 1,156,832.
// ---------------------------------------------------------------------------
__global__ __launch_bounds__(256) void prep_kernel(
    const float* __restrict__ W1, const float* __restrict__ W2,
    const float* __restrict__ U1, const float* __restrict__ U2,
    u16* __restrict__ W1T, u16* __restrict__ W2T,
    u16* __restrict__ U1T, u16* __restrict__ U2T,
    u32* __restrict__ hb1, u32* __restrict__ hb2, u32* __restrict__ ctrl)
{
    int i = blockIdx.x * 256 + threadIdx.x;
    if (i < 240000) { int j = i / 200, k = i - j * 200; W1T[i] = f2bf(W1[k * 1200 + j]); return; }
    i -= 240000;
    if (i < 240000) { int j = i / 400, k = i - j * 400; W2T[i] = f2bf(W2[k * 600 + j]); return; }
    i -= 240000;
    if (i < 480000) { int j = i / 400, k = i - j * 400; U1T[i] = f2bf(U1[k * 1200 + j]); return; }
    i -= 480000;
    if (i < 120000) { int j = i / 200, k = i - j * 200; U2T[i] = f2bf(U2[k * 600 + j]); return; }
    i -= 120000;
    if (i < 51200) {   // hbuf1 slot 0 per group (6400 u32 x 8)
        int gg = i / 6400;
        hb1[(size_t)gg * 1638400 + (i - gg * 6400)] = 0u;
        return;
    }
    i -= 51200;
    if (i < 25600) {   // hbuf2 slot 0 per group (3200 u32 x 8)
        int gg = i / 3200;
        hb2[gg * 25600 + (i - gg * 3200)] = 0u;
        return;
    }
    i -= 25600;
    if (i < 32) ctrl[i] = 0u;   // clmA[8], clmB[8], sent1[8], sent2[8]
}

// ---------------------------------------------------------------------------
// embed + batchnorm -> x bf16, layout [t*128 + b][200]
// ---------------------------------------------------------------------------
__global__ __launch_bounds__(256) void embed_bn_kernel(
    const int* __restrict__ tokens, const float* __restrict__ emb,
    const float* __restrict__ gamma, const float* __restrict__ beta,
    const float* __restrict__ mmean, const float* __restrict__ mvar,
    u16* __restrict__ x)
{
    int gid = blockIdx.x * 256 + threadIdx.x;  // 6,553,600 total
    int r = gid / 200, e = gid - r * 200;
    int t = r >> 7, b = r & 127;               // r = t*128 + b
    int tok = tokens[b * 256 + t];
    float v = (emb[(size_t)tok * 200 + e] - mmean[e]) *
              (1.0f / sqrtf(mvar[e] + 1e-3f)) * gamma[e] + beta[e];
    x[gid] = f2bf(v);
}

// ---------------------------------------------------------------------------
// GEMM: C[M][N] (bf16) = A[M][KEL] @ B[KEL][N] + bias (B given as BT[N][KEL]).
// Used only for xw1 = x @ W1 + bi1.
// ---------------------------------------------------------------------------
template<int KEL, int KSTEPS, int KPAD>
__global__ __launch_bounds__(256) void gemm_bias_kernel(
    const u16* __restrict__ A, const u16* __restrict__ BT,
    const float* __restrict__ bias, u16* __restrict__ C, int N)
{
    __shared__ u16 A_lds[64 * KPAD];
    __shared__ u16 B_lds[64 * KPAD];
    const int m0 = blockIdx.x * 64, n0 = blockIdx.y * 64;
    const int tid = threadIdx.x;
    const int lane = tid & 63, wave = tid >> 6;
    const int l15 = lane & 15, lq = lane >> 4;

    for (int idx = tid; idx < 64 * (KPAD / 2); idx += 256) {
        int row = idx / (KPAD / 2), kp = idx % (KPAD / 2);
        int k = kp * 2;
        u32 va = (k < KEL) ? *(const u32*)(A + (size_t)(m0 + row) * KEL + k) : 0u;
        *(u32*)(A_lds + row * KPAD + k) = va;
        int gn = n0 + row;
        u32 vb = (k < KEL && gn < N) ? *(const u32*)(BT + (size_t)gn * KEL + k) : 0u;
        *(u32*)(B_lds + row * KPAD + k) = vb;
    }
    __syncthreads();

    f32x4 acc[4];
    for (int i = 0; i < 4; ++i) acc[i] = (f32x4){0.f, 0.f, 0.f, 0.f};
    for (int ks = 0; ks < KSTEPS; ++ks) {
        bf16x8 a = *(const bf16x8*)(A_lds + (wave * 16 + l15) * KPAD + ks * 32 + lq * 8);
        for (int nt = 0; nt < 4; ++nt) {
            bf16x8 b = *(const bf16x8*)(B_lds + (nt * 16 + l15) * KPAD + ks * 32 + lq * 8);
            acc[nt] = __builtin_amdgcn_mfma_f32_16x16x32_bf16(a, b, acc[nt], 0, 0, 0);
        }
    }
    for (int nt = 0; nt < 4; ++nt) {
        int col = n0 + nt * 16 + l15;
        if (col < N) {
            float bv = bias[col];
            for (int i = 0; i < 4; ++i) {
                int row = m0 + wave * 16 + lq * 4 + i;
                C[(size_t)row * N + col] = f2bf(acc[nt][i] + bv);
            }
        }
    }
}

// ---------------------------------------------------------------------------
// FUSED GRU1+GRU2 pipeline, 192 WGs x 256 threads.
// NEW (round 10): SENTINEL-GATED exchange (round-9-proven mechanism) replaces
// per-slot tag polling on BOTH exchanges:
//   producer: tagged h stores (unchanged) -> vmcnt(0) drain -> barrier ->
//             tid0 atomicAdd(sent[g]) -> output stores.
//   consumer: spin on ONE u32 (sent[g] >= K*t; one VMEM req per wave; the
//             drain of older stores hides under the inevitable wait) ->
//             ONE single-pass bulk load of the slot, no validation/retry.
// hbuf1 = FULL 256-deep ring (no WAR ever; GRU2 reads o1 directly from it —
// the o1b buffer and its per-step stores/drain are gone). hbuf2 = depth-8
// ring (lockstep induction: a producer at step t passed sent2>=8t, so every
// peer finished reading slot (t-7)&7 long before it is overwritten).
// hbuf1 bulk loads are PLAIN (each address read once per launch; validated
// by round-9's o1b path); hbuf2 bulk loads stay agent-atomic (addresses
// reuse every 8 steps -> must bypass L1).
// Deadlock-free: GRU1 waits only on sent1 (symmetric peers); GRU2 waits on
// sent1 (GRU1 independent progress) + sent2 (symmetric peers). No cycles.
// ---------------------------------------------------------------------------
__global__ __launch_bounds__(256) void fused_gru_kernel(
    const u16* __restrict__ xw1,     // [256*128][1200] bf16
    const u16* __restrict__ U1T,     // [1200][400] bf16
    const float* __restrict__ br1,   // [1200] recurrent bias GRU1
    const u16* __restrict__ W2T,     // [600][400] bf16
    const u16* __restrict__ U2T,     // [600][200] bf16
    const float* __restrict__ b2,    // [2][600]: bi2 then br2
    const int* __restrict__ tokens,  // [128][256]
    float* __restrict__ out1,        // [128][256][400]
    float* __restrict__ h1f,         // [128][400]
    float* __restrict__ out2,        // [128][256][200]
    float* __restrict__ h2f,         // [128][200]
    u32* __restrict__ hbuf1,         // [8][256][16][400] tagged u32 (full ring)
    u32* __restrict__ hbuf2,         // [8][8][16][200] tagged u32
    u32* __restrict__ ctrl)          // [32]: clmA[8], clmB[8], sent1[8], sent2[8]
{
    __shared__ __align__(16) char smem[140288];
    __shared__ int claim_s[3];
    const int tid = threadIdx.x;

    // --- role + XCD-affinity claim (GRU1 slots first, then GRU2) ---
    if (tid == 0) {
        u32 xcc;
        asm volatile("s_getreg_b32 %0, hwreg(HW_REG_XCC_ID)" : "=s"(xcc));
        int x = (int)(xcc & 7u);
        int role = -1, cg = -1, cw = -1;
        for (int a = 0; a < 8 && role < 0; ++a) {
            int gg = (x + a) & 7;
            u32 ww = atomicAdd(&ctrl[gg], 1u);
            if (ww < 16u) { role = 0; cg = gg; cw = (int)ww; }
        }
        for (int a = 0; a < 8 && role < 0; ++a) {
            int gg = (x + a) & 7;
            u32 ww = atomicAdd(&ctrl[8 + gg], 1u);
            if (ww < 8u) { role = 1; cg = gg; cw = (int)ww; }
        }
        claim_s[0] = role; claim_s[1] = cg; claim_s[2] = cw;
    }
    __syncthreads();
    const int role = claim_s[0], g = claim_s[1], w = claim_s[2];
    const int b0 = g * 16;
    const int lane = tid & 63, wave = tid >> 6;
    const int l15 = lane & 15, lq = lane >> 4;

    if (role == 0) {
        // ===================== GRU1 =====================
        u16* U_lds = (u16*)smem;                       // 80*424*2 = 67840
        u16* h_lds = (u16*)(smem + 67840);             // 16*424*2 = 13568
        float* rec_lds = (float*)(smem + 81408);       // 16*80*4  = 5120
        unsigned char* tok_lds = (unsigned char*)(smem + 86528);  // 4096

        for (int i = tid; i < 16960; i += 256) ((u32*)U_lds)[i] = 0u;
        for (int i = tid; i < 3392; i += 256) ((u32*)h_lds)[i] = 0u;
        __syncthreads();
        for (int idx = tid; idx < 15000; idx += 256) {      // 75 cols x 200
            int c = idx / 200, kp = idx - (idx / 200) * 200;
            int j = (c / 25) * 400 + w * 25 + (c % 25);
            *(u32*)(U_lds + c * 424 + kp * 2) =
                *(const u32*)(U1T + (size_t)j * 400 + kp * 2);
        }
        for (int i = tid; i < 4096; i += 256) {
            int b = i >> 8, tt = i & 255;
            tok_lds[i] = (tokens[(b0 + b) * 256 + tt] != 0) ? 1 : 0;
        }

        int ne = 0;
        int eb[2], eco[2], eih[2], egb[2], exw[2];
        float ebrz[2], ebrr[2], ebrh[2], hold[2];
        for (int u = tid; u < 400; u += 256) {
            int b = u / 25, co = u % 25;
            int ih = w * 25 + co;
            eb[ne] = b; eco[ne] = co; eih[ne] = ih; egb[ne] = b0 + b;
            exw[ne] = (b0 + b) * 1200;
            ebrz[ne] = br1[ih]; ebrr[ne] = br1[400 + ih]; ebrh[ne] = br1[800 + ih];
            hold[ne] = 0.f; ++ne;
        }
        // bulk-load mapping: s-th u64 covers (b = s/200, kk = s%200) col pair
        int loff[13];
        for (int i = 0; i < 13; ++i) {
            int s = tid + i * 256;
            loff[i] = (s < 3200) ? ((s / 200) * 424 + (s % 200) * 2) : 0;
        }
        u32* hb = hbuf1 + (size_t)g * 1638400;

        for (int t = 0; t < 256; ++t) {
            // 1. x prefetch (latency hides under the sentinel wait)
            float xzv[2], xrv[2], xhv[2];
            for (int e = 0; e < ne; ++e) {
                const u16* xr = xw1 + (size_t)t * 153600 + exw[e];
                xzv[e] = bf2f(xr[eih[e]]);
                xrv[e] = bf2f(xr[400 + eih[e]]);
                xhv[e] = bf2f(xr[800 + eih[e]]);
            }

            // 2. sentinel wait: all 16 peers have published h(t)
            const u32 need = 16u * (u32)t;
            while (__hip_atomic_load(&ctrl[16 + g], __ATOMIC_RELAXED,
                                     __HIP_MEMORY_SCOPE_AGENT) < need)
                __builtin_amdgcn_s_sleep(1);
            asm volatile("" ::: "memory");

            // 3. single-pass bulk load of slot t (plain u64, unpack tags)
            const u64* src = (const u64*)(hb + (size_t)t * 6400);
            #pragma unroll
            for (int i = 0; i < 13; ++i) {
                int s = tid + i * 256;
                if (s < 3200) {
                    u64 v = src[s];
                    *(u32*)(h_lds + loff[i]) =
                        ((u32)(v >> 16) & 0xFFFFu) | ((u32)(v >> 48) << 16);
                }
            }
            __syncthreads();

            // 4. rec = h @ U-slice (MFMA 16x16x32)
            f32x4 acc[2];
            acc[0] = (f32x4){0.f, 0.f, 0.f, 0.f};
            acc[1] = (f32x4){0.f, 0.f, 0.f, 0.f};
            for (int ks = 0; ks < 13; ++ks) {
                bf16x8 a = *(const bf16x8*)(h_lds + l15 * 424 + ks * 32 + lq * 8);
                int ti = 0;
                for (int nt = wave; nt < 5; nt += 4, ++ti) {
                    bf16x8 b = *(const bf16x8*)(U_lds + (nt * 16 + l15) * 424 + ks * 32 + lq * 8);
                    acc[ti] = __builtin_amdgcn_mfma_f32_16x16x32_bf16(a, b, acc[ti], 0, 0, 0);
                }
            }
            {
                int ti = 0;
                for (int nt = wave; nt < 5; nt += 4, ++ti)
                    for (int i = 0; i < 4; ++i)
                        rec_lds[(lq * 4 + i) * 80 + nt * 16 + l15] = acc[ti][i];
            }
            __syncthreads();

            // 5. gates -> publish h(t+1) -> drain -> sentinel -> outputs
            u32* hd = hb + (size_t)((t + 1) & 255) * 6400;
            float hnv[2]; u32 tgv[2];
            for (int e = 0; e < ne; ++e) {
                int b = eb[e], co = eco[e];
                float rz = rec_lds[b * 80 + co] + ebrz[e];
                float rr = rec_lds[b * 80 + 25 + co] + ebrr[e];
                float rh = rec_lds[b * 80 + 50 + co] + ebrh[e];
                float z = 1.f / (1.f + __expf(-(xzv[e] + rz)));
                float r = 1.f / (1.f + __expf(-(xrv[e] + rr)));
                float pre = xhv[e] + r * rh;
                float th = 2.f / (1.f + __expf(-2.f * pre)) - 1.f;
                float hn = z * hold[e] + (1.f - z) * th;
                if (!tok_lds[b * 256 + t]) hn = hold[e];
                hold[e] = hn; hnv[e] = hn;
                tgv[e] = ((u32)f2bf(hn) << 16) | (u32)(t + 1);
            }
            for (int e = 0; e < ne; ++e)
                __hip_atomic_store(hd + eb[e] * 400 + eih[e], tgv[e],
                                   __ATOMIC_RELAXED, __HIP_MEMORY_SCOPE_AGENT);
            asm volatile("s_waitcnt vmcnt(0)" ::: "memory");
            __syncthreads();
            if (tid == 0)
                __hip_atomic_fetch_add(&ctrl[16 + g], 1u, __ATOMIC_RELAXED,
                                       __HIP_MEMORY_SCOPE_AGENT);
            for (int e = 0; e < ne; ++e) {
                int gb = egb[e], ih = eih[e];
                out1[((size_t)gb * 256 + t) * 400 + ih] = hnv[e];
                if (t == 255) h1f[(size_t)gb * 400 + ih] = hnv[e];
            }
        }
    } else {
        // ===================== GRU2 =====================
        u16* W2_lds = (u16*)smem;                      // 80*424*2 = 67840
        u16* U2_lds = (u16*)(smem + 67840);            // 80*232*2 = 37120
        u16* o1_lds = (u16*)(smem + 104960);           // 16*424*2 = 13568
        u16* h2_lds = (u16*)(smem + 118528);           // 16*232*2 = 7424
        float* xw_lds = (float*)(smem + 125952);       // 16*80*4 = 5120
        float* rc_lds = (float*)(smem + 131072);       // 16*80*4 = 5120
        unsigned char* tok_lds = (unsigned char*)(smem + 136192); // 4096

        for (int i = tid; i < 31488; i += 256) ((u32*)smem)[i] = 0u; // u16 regions
        __syncthreads();
        for (int idx = tid; idx < 15000; idx += 256) {     // W2 slice 75x400
            int c = idx / 200, kp = idx - (idx / 200) * 200;
            int j = (c / 25) * 200 + w * 25 + (c % 25);
            *(u32*)(W2_lds + c * 424 + kp * 2) =
                *(const u32*)(W2T + (size_t)j * 400 + kp * 2);
        }
        for (int idx = tid; idx < 7500; idx += 256) {      // U2 slice 75x200
            int c = idx / 100, kp = idx - (idx / 100) * 100;
            int j = (c / 25) * 200 + w * 25 + (c % 25);
            *(u32*)(U2_lds + c * 232 + kp * 2) =
                *(const u32*)(U2T + (size_t)j * 200 + kp * 2);
        }
        for (int i = tid; i < 4096; i += 256) {
            int b = i >> 8, tt = i & 255;
            tok_lds[i] = (tokens[(b0 + b) * 256 + tt] != 0) ? 1 : 0;
        }

        int ne = 0;
        int eb[2], eco[2], eih[2], egb[2];
        float ebiz[2], ebir[2], ebih[2], ebrz[2], ebrr[2], ebrh[2], hold[2];
        for (int u = tid; u < 400; u += 256) {
            int b = u / 25, co = u % 25;
            int ih = w * 25 + co;
            eb[ne] = b; eco[ne] = co; eih[ne] = ih; egb[ne] = b0 + b;
            ebiz[ne] = b2[ih];       ebir[ne] = b2[200 + ih];  ebih[ne] = b2[400 + ih];
            ebrz[ne] = b2[600 + ih]; ebrr[ne] = b2[800 + ih];  ebrh[ne] = b2[1000 + ih];
            hold[ne] = 0.f; ++ne;
        }
        int loffA[13], loffB[7];
        for (int i = 0; i < 13; ++i) {
            int s = tid + i * 256;
            loffA[i] = (s < 3200) ? ((s / 200) * 424 + (s % 200) * 2) : 0;
        }
        for (int i = 0; i < 7; ++i) {
            int s = tid + i * 256;
            loffB[i] = (s < 1600) ? ((s / 100) * 232 + (s % 100) * 2) : 0;
        }
        u32* hb1g = hbuf1 + (size_t)g * 1638400;
        u32* hb2 = hbuf2 + g * 25600;
        __syncthreads();

        for (int t = 0; t < 256; ++t) {
            // 1. wait GRU1 group g published h1(t+1) = out1[t]
            const u32 need1 = 16u * (u32)(t + 1);
            while (__hip_atomic_load(&ctrl[16 + g], __ATOMIC_RELAXED,
                                     __HIP_MEMORY_SCOPE_AGENT) < need1)
                __builtin_amdgcn_s_sleep(2);
            asm volatile("" ::: "memory");

            // 2. bulk o1(t) from hbuf1 slot (t+1) (plain u64, unpack)
            const u64* srcA = (const u64*)(hb1g + (size_t)((t + 1) & 255) * 6400);
            #pragma unroll
            for (int i = 0; i < 13; ++i) {
                int s = tid + i * 256;
                if (s < 3200) {
                    u64 v = srcA[s];
                    *(u32*)(o1_lds + loffA[i]) =
                        ((u32)(v >> 16) & 0xFFFFu) | ((u32)(v >> 48) << 16);
                }
            }

            // 3. wait own peers published h2(t), bulk (atomic: ring reuses)
            const u32 need2 = 8u * (u32)t;
            while (__hip_atomic_load(&ctrl[24 + g], __ATOMIC_RELAXED,
                                     __HIP_MEMORY_SCOPE_AGENT) < need2)
                __builtin_amdgcn_s_sleep(1);
            asm volatile("" ::: "memory");
            const u64* srcB = (const u64*)(hb2 + (size_t)(t & 7) * 3200);
            #pragma unroll
            for (int i = 0; i < 7; ++i) {
                int s = tid + i * 256;
                if (s < 1600) {
                    u64 v = __hip_atomic_load(srcB + s, __ATOMIC_RELAXED,
                                              __HIP_MEMORY_SCOPE_AGENT);
                    *(u32*)(h2_lds + loffB[i]) =
                        ((u32)(v >> 16) & 0xFFFFu) | ((u32)(v >> 48) << 16);
                }
            }
            __syncthreads();

            // 4. MFMA: xw-part (o1 @ W2slice, K=400) + rec-part (h2 @ U2slice, K=200)
            f32x4 aw[2], au[2];
            aw[0] = (f32x4){0.f,0.f,0.f,0.f}; aw[1] = (f32x4){0.f,0.f,0.f,0.f};
            au[0] = (f32x4){0.f,0.f,0.f,0.f}; au[1] = (f32x4){0.f,0.f,0.f,0.f};
            for (int ks = 0; ks < 13; ++ks) {
                bf16x8 a = *(const bf16x8*)(o1_lds + l15 * 424 + ks * 32 + lq * 8);
                int ti = 0;
                for (int nt = wave; nt < 5; nt += 4, ++ti) {
                    bf16x8 b = *(const bf16x8*)(W2_lds + (nt * 16 + l15) * 424 + ks * 32 + lq * 8);
                    aw[ti] = __builtin_amdgcn_mfma_f32_16x16x32_bf16(a, b, aw[ti], 0, 0, 0);
                }
            }
            for (int ks = 0; ks < 7; ++ks) {
                bf16x8 a = *(const bf16x8*)(h2_lds + l15 * 232 + ks * 32 + lq * 8);
                int ti = 0;
                for (int nt = wave; nt < 5; nt += 4, ++ti) {
                    bf16x8 b = *(const bf16x8*)(U2_lds + (nt * 16 + l15) * 232 + ks * 32 + lq * 8);
                    au[ti] = __builtin_amdgcn_mfma_f32_16x16x32_bf16(a, b, au[ti], 0, 0, 0);
                }
            }
            {
                int ti = 0;
                for (int nt = wave; nt < 5; nt += 4, ++ti)
                    for (int i = 0; i < 4; ++i) {
                        xw_lds[(lq * 4 + i) * 80 + nt * 16 + l15] = aw[ti][i];
                        rc_lds[(lq * 4 + i) * 80 + nt * 16 + l15] = au[ti][i];
                    }
            }
            __syncthreads();

            // 5. gates -> publish h2(t+1) -> drain -> sentinel -> outputs
            u32* hd = hb2 + (size_t)((t + 1) & 7) * 3200;
            float hnv[2]; u32 tgv[2];
            for (int e = 0; e < ne; ++e) {
                int b = eb[e], co = eco[e];
                float xz = xw_lds[b * 80 + co] + ebiz[e];
                float rz = rc_lds[b * 80 + co] + ebrz[e];
                float xr = xw_lds[b * 80 + 25 + co] + ebir[e];
                float rr = rc_lds[b * 80 + 25 + co] + ebrr[e];
                float xh = xw_lds[b * 80 + 50 + co] + ebih[e];
                float rh = rc_lds[b * 80 + 50 + co] + ebrh[e];
                float z = 1.f / (1.f + __expf(-(xz + rz)));
                float r = 1.f / (1.f + __expf(-(xr + rr)));
                float pre = xh + r * rh;
                float th = 2.f / (1.f + __expf(-2.f * pre)) - 1.f;
                float hn = z * hold[e] + (1.f - z) * th;
                if (!tok_lds[b * 256 + t]) hn = hold[e];
                hold[e] = hn; hnv[e] = hn;
                tgv[e] = ((u32)f2bf(hn) << 16) | (u32)(t + 1);
            }
            for (int e = 0; e < ne; ++e)
                __hip_atomic_store(hd + eb[e] * 200 + eih[e], tgv[e],
                                   __ATOMIC_RELAXED, __HIP_MEMORY_SCOPE_AGENT);
            asm volatile("s_waitcnt vmcnt(0)" ::: "memory");
            __syncthreads();
            if (tid == 0)
                __hip_atomic_fetch_add(&ctrl[24 + g], 1u, __ATOMIC_RELAXED,
                                       __HIP_MEMORY_SCOPE_AGENT);
            for (int e = 0; e < ne; ++e) {
                int gb = egb[e], ih = eih[e];
                out2[((size_t)gb * 256 + t) * 200 + ih] = hnv[e];
                if (t == 255) h2f[(size_t)gb * 200 + ih] = hnv[e];
            }
        }
    }
}

// ---------------------------------------------------------------------------
// launch
// ---------------------------------------------------------------------------
extern "C" void kernel_launch(void* const* d_in, const int* in_sizes, int n_in,
                              void* d_out, int out_size, void* d_ws, size_t ws_size,
                              hipStream_t stream)
{
    const int*   tokens = (const int*)d_in[0];
    const float* emb    = (const float*)d_in[1];
    const float* gamma  = (const float*)d_in[2];
    const float* beta   = (const float*)d_in[3];
    const float* mmean  = (const float*)d_in[4];
    const float* mvar   = (const float*)d_in[5];
    const float* W1     = (const float*)d_in[6];
    const float* U1     = (const float*)d_in[7];
    const float* b1     = (const float*)d_in[8];
    const float* W2     = (const float*)d_in[9];
    const float* U2     = (const float*)d_in[10];
    const float* b2     = (const float*)d_in[11];

    float* out = (float*)d_out;
    char* ws = (char*)d_ws;

    u16* x     = (u16*)(ws + 0);            // 13,107,200
    u16* xw1   = (u16*)(ws + 13107200);     // 78,643,200 -> 91,750,400
    u16* W1T   = (u16*)(ws + 91750400);     // 480,000    -> 92,230,400
    u16* W2T   = (u16*)(ws + 92230400);     // 480,000    -> 92,710,400
    u16* U1T   = (u16*)(ws + 92710400);     // 960,000    -> 93,670,400
    u16* U2T   = (u16*)(ws + 93670400);     // 240,000    -> 93,910,400
    u32* hbuf1 = (u32*)(ws + 93910400);     // 8*256*6400*4 = 52,428,800 -> 146,339,200
    u32* hbuf2 = (u32*)(ws + 146339200);    // 8*8*3200*4 = 819,200 -> 147,158,400
    u32* ctrl  = (u32*)(ws + 147158400);    // 32 u32

    float* out2 = out;              // [128,256,200]
    float* out1 = out + 6553600;    // [128,256,400]
    float* h2   = out + 19660800;   // [128,200]
    float* h1   = out + 19686400;   // [128,400]

    // items: 1,080,000 weights + 51,200 + 25,600 + 32 = 1,156,832
    prep_kernel<<<4519, 256, 0, stream>>>(W1, W2, U1, U2, W1T, W2T, U1T, U2T,
                                          hbuf1, hbuf2, ctrl);
    embed_bn_kernel<<<25600, 256, 0, stream>>>(tokens, emb, gamma, beta, mmean,
                                               mvar, x);
    // xw1 = x @ W1 + bi1   ([32768,200]@[200,1200])
    gemm_bias_kernel<200, 7, 232><<<dim3(512, 19), 256, 0, stream>>>(
        x, W1T, b1, xw1, 1200);
    // fused GRU1 (128 WGs) + GRU2 (64 WGs) pipeline
    fused_gru_kernel<<<192, 256, 0, stream>>>(
        xw1, U1T, b1 + 1200, W2T, U2T, b2, tokens,
        out1, h1, out2, h2, hbuf1, hbuf2, ctrl);
}